// Round 18
// baseline (207.844 us; speedup 1.0000x reference)
//
#include <hip/hip_runtime.h>
#include <hip/hip_bf16.h>
#include <math.h>

// Problem constants
#define BB      4
#define NN      2048
#define DM      768
#define NH      8
#define DHH     96
#define BH      (BB*NH)          // 32
#define MROWS   (BB*NN)          // 8192
#define NC_QKV  (3*DM)           // 2304

typedef short v4s  __attribute__((ext_vector_type(4)));
typedef short v8s  __attribute__((ext_vector_type(8)));
typedef float v4f  __attribute__((ext_vector_type(4)));
typedef float v16f __attribute__((ext_vector_type(16)));
typedef unsigned int u32;

// log2(e)/sqrt(96) folded into Q at QKV-GEMM epilogue
#define SCQ 0.14724599350930152f

static __device__ __forceinline__ ushort f2bf(float f) {
    __hip_bfloat16 h = __float2bfloat16(f);
    return *reinterpret_cast<ushort*>(&h);
}

static __device__ __forceinline__ void gload_lds16(const ushort* g, ushort* l) {
    __builtin_amdgcn_global_load_lds(
        (const __attribute__((address_space(1))) void*)g,
        (__attribute__((address_space(3))) void*)l, 16, 0, 0);
}

// two 8B LDS loads 32B apart -> one v8s A-fragment (k-permutation pi)
static __device__ __forceinline__ v8s load2x4_o16(const ushort* p) {
    union { v4s h[2]; v8s s; } x;
    x.h[0] = *reinterpret_cast<const v4s*>(p);
    x.h[1] = *reinterpret_cast<const v4s*>(p + 16);
    return x.s;
}

static __device__ __forceinline__ v8s pack4(u32 a, u32 b, u32 c, u32 d) {
    union { u32 u[4]; v8s s; } x;
    x.u[0] = a; x.u[1] = b; x.u[2] = c; x.u[3] = d;
    return x.s;
}
static __device__ __forceinline__ u32 bfpair(float lo, float hi) {
    return (u32)f2bf(lo) | ((u32)f2bf(hi) << 16);
}

// ---------------------------------------------------------------------------
// fp32 -> bf16 elementwise (n8 = count/8)
// ---------------------------------------------------------------------------
__global__ __launch_bounds__(256)
void conv_bf16(const float* __restrict__ in, ushort* __restrict__ out, int n8)
{
    int i = blockIdx.x * 256 + threadIdx.x;
    if (i >= n8) return;
    const float4* p = reinterpret_cast<const float4*>(in) + (size_t)i * 2;
    float4 a = p[0], b = p[1];
    ushort r[8] = {f2bf(a.x), f2bf(a.y), f2bf(a.z), f2bf(a.w),
                   f2bf(b.x), f2bf(b.y), f2bf(b.z), f2bf(b.w)};
    *reinterpret_cast<v8s*>(out + (size_t)i * 8) = *reinterpret_cast<v8s*>(r);
}

// ---------------------------------------------------------------------------
// fp32 W[K][N] -> bf16 Wt[N][K], BOTH weight matrices in one launch
// ---------------------------------------------------------------------------
__global__ __launch_bounds__(256)
void convT2_bf16(const float* __restrict__ Wq, ushort* __restrict__ Wqt,
                 const float* __restrict__ Wo, ushort* __restrict__ Wot)
{
    __shared__ ushort t[32][33];
    const int K = DM;
    const bool isQ = (blockIdx.y < NC_QKV / 32);
    const float*  W  = isQ ? Wq  : Wo;
    ushort*       Wt = isQ ? Wqt : Wot;
    const int N  = isQ ? NC_QKV : DM;
    const int k0 = blockIdx.x * 32;
    const int n0 = (isQ ? blockIdx.y : blockIdx.y - NC_QKV / 32) * 32;
    const int tx = threadIdx.x & 31, ty = threadIdx.x >> 5;
    #pragma unroll
    for (int r = ty; r < 32; r += 8)
        t[tx][r] = f2bf(W[(size_t)(k0 + r) * N + n0 + tx]);
    __syncthreads();
    #pragma unroll
    for (int r = ty; r < 32; r += 8)
        Wt[(size_t)(n0 + r) * K + k0 + tx] = t[r][tx];
}

// ---------------------------------------------------------------------------
// bf16 MFMA GEMM: C[M][Ncols] = A[M][K] @ Bt[Ncols][K]^T + bias
// NEW: 4-slot ring buffer at BK=32 chunk granularity -> 3-deep prefetch
// (~1000+ cyc lookahead > ~900 cyc HBM latency; the 1-deep variants all
// measured ~equal because their single-phase lookahead ~600 cyc < latency).
// Protocol per chunk c: STAGE(c+3) -> s_waitcnt vmcnt(12) [chunk c landed,
// c+1..c+3 = 12 ops in flight] -> s_barrier -> compute(c) -> s_barrier.
// sched_barrier(0) fences around waits/barriers (hoist hazard, rule #18).
// Ring safety: slot(c+3)=(c+3)&3 disjoint from {c,c+1,c+2}&3; WAR on slot
// (c-1)&3 covered by the end-barrier of iteration c-1. All waves issue
// identical load counts (uniform vmcnt). LDS 64KB -> 2 blocks/CU (as before).
// ---------------------------------------------------------------------------
template<int SCATTER>
__global__ __launch_bounds__(256)
void gemm_mfma(const ushort* __restrict__ A, const ushort* __restrict__ Bt,
               const float* __restrict__ bias, void* __restrict__ outp,
               int K, int Ncols)
{
    __shared__ ushort As[4][4096];   // [slot][4 kslots][128 rows][8]
    __shared__ ushort Bs[4][4096];

    const int tid  = threadIdx.x;
    const int lane = tid & 63;
    const int wv   = tid >> 6;
    const int l31  = lane & 31;
    const int lhi  = lane >> 5;
    const int wr   = wv >> 1, wc = wv & 1;

    // XCD supertile swizzle (gridDim.x==64, gridDim.y even)
    const int ny   = gridDim.y;
    const int id   = blockIdx.y * gridDim.x + blockIdx.x;
    const int c8   = id & 7;
    const int j    = id >> 3;
    const int hy   = (j >= (ny >> 1) * 8) ? 1 : 0;
    const int w    = j - hy * (ny >> 1) * 8;
    const int bx   = c8 * 8 + (w & 7);
    const int by   = hy * (ny >> 1) + (w >> 3);
    const int row0 = bx * 128;
    const int col0 = by * 128;

    v16f acc[2][2];
    #pragma unroll
    for (int mi = 0; mi < 2; ++mi)
        #pragma unroll
        for (int nj = 0; nj < 2; ++nj)
            #pragma unroll
            for (int i = 0; i < 16; ++i) acc[mi][nj][i] = 0.0f;

// stage one BK=32 chunk (ch) into ring slot sl: 4 gload_lds per thread
#define STAGE_C(sl, ch) do {                                                    \
    const int kk_ = (ch) * 32;                                                  \
    _Pragma("unroll")                                                           \
    for (int c_ = 0; c_ < 2; ++c_) {                                            \
        const int idx_ = c_ * 256 + tid;       /* 0..511 */                     \
        const int ss_  = idx_ >> 7;            /* kslot 0..3 */                 \
        const int rr_  = idx_ & 127;           /* row */                        \
        gload_lds16(&A [(size_t)(row0 + rr_) * K + kk_ + ss_ * 8],              \
                    &As[sl][(c_ * 256 + wv * 64) * 8]);                         \
        gload_lds16(&Bt[(size_t)(col0 + rr_) * K + kk_ + ss_ * 8],              \
                    &Bs[sl][(c_ * 256 + wv * 64) * 8]);                         \
    }                                                                           \
} while (0)

// compute one BK=32 chunk from ring slot sl: 8 MFMAs per wave
#define COMPUTE_C(sl) do {                                                      \
    _Pragma("unroll")                                                           \
    for (int s16_ = 0; s16_ < 2; ++s16_) {                                      \
        const int ks_ = s16_ * 2 + lhi;        /* 0..3 */                       \
        v8s a0_ = *reinterpret_cast<const v8s*>(&As[sl][(ks_ * 128 + 64 * wr + l31) * 8]);          \
        v8s a1_ = *reinterpret_cast<const v8s*>(&As[sl][(ks_ * 128 + 64 * wr + 32 + l31) * 8]);     \
        v8s b0_ = *reinterpret_cast<const v8s*>(&Bs[sl][(ks_ * 128 + 64 * wc + l31) * 8]);          \
        v8s b1_ = *reinterpret_cast<const v8s*>(&Bs[sl][(ks_ * 128 + 64 * wc + 32 + l31) * 8]);     \
        acc[0][0] = __builtin_amdgcn_mfma_f32_32x32x16_bf16(a0_, b0_, acc[0][0], 0, 0, 0);          \
        acc[0][1] = __builtin_amdgcn_mfma_f32_32x32x16_bf16(a0_, b1_, acc[0][1], 0, 0, 0);          \
        acc[1][0] = __builtin_amdgcn_mfma_f32_32x32x16_bf16(a1_, b0_, acc[1][0], 0, 0, 0);          \
        acc[1][1] = __builtin_amdgcn_mfma_f32_32x32x16_bf16(a1_, b1_, acc[1][1], 0, 0, 0);          \
    }                                                                           \
} while (0)

#define FENCE() __builtin_amdgcn_sched_barrier(0)
#define BARRIER() do { FENCE(); __builtin_amdgcn_s_barrier(); FENCE(); } while (0)

    const int nc = K >> 5;               // 24 chunks (K=768 both GEMMs)

    // prologue: 3 chunks in flight
    STAGE_C(0, 0);
    STAGE_C(1, 1);
    STAGE_C(2, 2);

    // main loop: c = 0 .. nc-4 (uniform across all blocks/waves)
    for (int ch = 0; ch + 3 < nc; ++ch) {
        STAGE_C((ch + 3) & 3, ch + 3);
        asm volatile("s_waitcnt vmcnt(12)" ::: "memory");  // chunk ch landed
        BARRIER();                                          // ... for ALL waves
        COMPUTE_C(ch & 3);
        BARRIER();                                          // WAR: reads done
    }
    // epilogue: chunks nc-3, nc-2, nc-1
    asm volatile("s_waitcnt vmcnt(8)" ::: "memory");
    BARRIER();
    COMPUTE_C((nc - 3) & 3);
    BARRIER();
    asm volatile("s_waitcnt vmcnt(4)" ::: "memory");
    BARRIER();
    COMPUTE_C((nc - 2) & 3);
    BARRIER();
    asm volatile("s_waitcnt vmcnt(0)" ::: "memory");
    BARRIER();
    COMPUTE_C((nc - 1) & 3);

#undef STAGE_C
#undef COMPUTE_C
#undef FENCE
#undef BARRIER

    #pragma unroll
    for (int nj = 0; nj < 2; ++nj) {
        const int c = col0 + 64 * wc + 32 * nj + l31;
        const float bv = bias[c];
        #pragma unroll
        for (int mi = 0; mi < 2; ++mi) {
            #pragma unroll
            for (int r = 0; r < 16; ++r) {
                const int m = row0 + 64 * wr + 32 * mi + (r & 3) + 8 * (r >> 2) + 4 * lhi;
                float v = acc[mi][nj][r] + bv;
                if (SCATTER) {
                    const int s   = c / DM;
                    const int rem = c - s * DM;
                    const int h   = rem / DHH;
                    const int d   = rem - h * DHH;
                    const int b   = m >> 11;
                    const int n   = m & (NN - 1);
                    if (s == 0) v *= SCQ;
                    ((ushort*)outp)[((size_t)(s * BH + b * NH + h) * NN + n) * DHH + d] = f2bf(v);
                } else {
                    ((float*)outp)[(size_t)m * Ncols + c] = v;
                }
            }
        }
    }
}

// ---------------------------------------------------------------------------
// MFMA bf16 flash attention (round-14 kernel, frozen: best measured, 94us).
// ---------------------------------------------------------------------------
__global__ __launch_bounds__(256, 2)
void attn_mfma(const ushort* __restrict__ qkv, ushort* __restrict__ attnout)
{
    __shared__ ushort Ks[6144];        // [g=d/8:12][kv=64][8]
    __shared__ ushort Vt[96][68];      // [d][kv], pad 68 (conflict-free)

    const int tid  = threadIdx.x;
    const int lane = tid & 63;
    const int wv   = tid >> 6;          // 0..3
    const int l15  = lane & 15;
    const int g4   = lane >> 4;         // 0..3

    // bh-clustered XCD swizzle (grid = (16 qblk, 32 bh)): 4 bh per XCD
    const int id   = blockIdx.y * gridDim.x + blockIdx.x;   // 0..511
    const int c8   = id & 7;
    const int j    = id >> 3;            // 0..63
    const int bh   = c8 * 4 + (j & 3);
    const int qblk = j >> 2;             // 0..15
    const int q0   = qblk * 128;
    const int b    = bh >> 3, h = bh & 7;

    const ushort* Qg = qkv + (size_t)bh * NN * DHH;
    const ushort* Kg = qkv + ((size_t)BH + bh) * NN * DHH;
    const ushort* Vg = qkv + ((size_t)2 * BH + bh) * NN * DHH;

    v8s qf[2][3];
    #pragma unroll
    for (int qt = 0; qt < 2; ++qt)
        #pragma unroll
        for (int c = 0; c < 3; ++c)
            qf[qt][c] = *reinterpret_cast<const v8s*>(
                &Qg[(size_t)(q0 + wv * 32 + qt * 16 + l15) * DHH + c * 32 + g4 * 8]);

    v4f o[2][6];
    #pragma unroll
    for (int qt = 0; qt < 2; ++qt)
        #pragma unroll
        for (int dt = 0; dt < 6; ++dt)
            #pragma unroll
            for (int i = 0; i < 4; ++i) o[qt][dt][i] = 0.0f;
    float ds[2] = {0.0f, 0.0f};

    // ---- prologue: stage tile 0 -> LDS
    {
        const size_t rowb = (size_t)lane * DHH;
        v8s kr[3], vr[3];
        #pragma unroll
        for (int i = 0; i < 3; ++i) {
            kr[i] = *reinterpret_cast<const v8s*>(&Kg[rowb + (wv * 3 + i) * 8]);
            vr[i] = *reinterpret_cast<const v8s*>(&Vg[rowb + (i * 4 + wv) * 8]);
        }
        #pragma unroll
        for (int i = 0; i < 3; ++i) {
            *reinterpret_cast<v8s*>(&Ks[(wv * 3 + i) * 512 + lane * 8]) = kr[i];
            #pragma unroll
            for (int jj = 0; jj < 8; ++jj)
                Vt[(i * 4 + wv) * 8 + jj][lane] = (ushort)vr[i][jj];
        }
    }
    __syncthreads();

    for (int t = 0; t < 32; ++t) {
        v8s kr0, kr1, kr2, vr0, vr1, vr2;
        if (t < 31) {
            const size_t rowb = (size_t)((t + 1) * 64 + lane) * DHH;
            kr0 = *reinterpret_cast<const v8s*>(&Kg[rowb + (wv * 3 + 0) * 8]);
            kr1 = *reinterpret_cast<const v8s*>(&Kg[rowb + (wv * 3 + 1) * 8]);
            kr2 = *reinterpret_cast<const v8s*>(&Kg[rowb + (wv * 3 + 2) * 8]);
            vr0 = *reinterpret_cast<const v8s*>(&Vg[rowb + (0 * 4 + wv) * 8]);
            vr1 = *reinterpret_cast<const v8s*>(&Vg[rowb + (1 * 4 + wv) * 8]);
            vr2 = *reinterpret_cast<const v8s*>(&Vg[rowb + (2 * 4 + wv) * 8]);
        }

        #pragma unroll
        for (int th = 0; th < 2; ++th) {
            v4f s00, s01, s10, s11;
            #pragma unroll
            for (int i = 0; i < 4; ++i) {
                s00[i] = 0.0f; s01[i] = 0.0f; s10[i] = 0.0f; s11[i] = 0.0f;
            }
            __builtin_amdgcn_s_setprio(1);
            #pragma unroll
            for (int c = 0; c < 3; ++c) {
                v8s kf0 = *reinterpret_cast<const v8s*>(
                    &Ks[((c * 4 + g4) * 64 + (th * 2 + 0) * 16 + l15) * 8]);
                v8s kf1 = *reinterpret_cast<const v8s*>(
                    &Ks[((c * 4 + g4) * 64 + (th * 2 + 1) * 16 + l15) * 8]);
                s00 = __builtin_amdgcn_mfma_f32_16x16x32_bf16(kf0, qf[0][c], s00, 0, 0, 0);
                s01 = __builtin_amdgcn_mfma_f32_16x16x32_bf16(kf1, qf[0][c], s01, 0, 0, 0);
                s10 = __builtin_amdgcn_mfma_f32_16x16x32_bf16(kf0, qf[1][c], s10, 0, 0, 0);
                s11 = __builtin_amdgcn_mfma_f32_16x16x32_bf16(kf1, qf[1][c], s11, 0, 0, 0);
            }
            __builtin_amdgcn_s_setprio(0);

            v8s pf[2];
            #pragma unroll
            for (int qt = 0; qt < 2; ++qt) {
                const v4f& sa = qt ? s10 : s00;
                const v4f& sb = qt ? s11 : s01;
                float e0[4], e1[4];
                #pragma unroll
                for (int r = 0; r < 4; ++r) {
                    e0[r] = exp2f(sa[r]);
                    e1[r] = exp2f(sb[r]);
                    ds[qt] += e0[r] + e1[r];
                }
                pf[qt] = pack4(bfpair(e0[0], e0[1]), bfpair(e0[2], e0[3]),
                               bfpair(e1[0], e1[1]), bfpair(e1[2], e1[3]));
            }

            __builtin_amdgcn_s_setprio(1);
            #pragma unroll
            for (int dt = 0; dt < 6; ++dt) {
                const ushort* vp = &Vt[dt * 16 + l15][th * 32 + g4 * 4];
                v8s va = load2x4_o16(vp);
                o[0][dt] = __builtin_amdgcn_mfma_f32_16x16x32_bf16(va, pf[0], o[0][dt], 0, 0, 0);
                o[1][dt] = __builtin_amdgcn_mfma_f32_16x16x32_bf16(va, pf[1], o[1][dt], 0, 0, 0);
            }
            __builtin_amdgcn_s_setprio(0);
        }

        if (t < 31) {
            __syncthreads();
            *reinterpret_cast<v8s*>(&Ks[(wv * 3 + 0) * 512 + lane * 8]) = kr0;
            *reinterpret_cast<v8s*>(&Ks[(wv * 3 + 1) * 512 + lane * 8]) = kr1;
            *reinterpret_cast<v8s*>(&Ks[(wv * 3 + 2) * 512 + lane * 8]) = kr2;
            #pragma unroll
            for (int jj = 0; jj < 8; ++jj) Vt[(0 * 4 + wv) * 8 + jj][lane] = (ushort)vr0[jj];
            #pragma unroll
            for (int jj = 0; jj < 8; ++jj) Vt[(1 * 4 + wv) * 8 + jj][lane] = (ushort)vr1[jj];
            #pragma unroll
            for (int jj = 0; jj < 8; ++jj) Vt[(2 * 4 + wv) * 8 + jj][lane] = (ushort)vr2[jj];
            __syncthreads();
        }
    }

    #pragma unroll
    for (int qt = 0; qt < 2; ++qt) {
        float d = ds[qt];
        d += __shfl_xor(d, 16, 64);
        d += __shfl_xor(d, 32, 64);
        const float inv = 1.0f / d;
        const int n = q0 + wv * 32 + qt * 16 + l15;
        ushort* orow = attnout + ((size_t)(b * NN + n)) * DM + h * DHH;
        #pragma unroll
        for (int dt = 0; dt < 6; ++dt) {
            const int d0 = dt * 16 + g4 * 4;
            uint2 pk;
            pk.x = bfpair(o[qt][dt][0] * inv, o[qt][dt][1] * inv);
            pk.y = bfpair(o[qt][dt][2] * inv, o[qt][dt][3] * inv);
            *reinterpret_cast<uint2*>(&orow[d0]) = pk;
        }
    }
}

// ---------------------------------------------------------------------------
extern "C" void kernel_launch(void* const* d_in, const int* in_sizes, int n_in,
                              void* d_out, int out_size, void* d_ws, size_t ws_size,
                              hipStream_t stream)
{
    (void)in_sizes; (void)n_in; (void)out_size; (void)ws_size;
    const float* x    = (const float*)d_in[0];
    const float* Wqkv = (const float*)d_in[1];
    const float* bqkv = (const float*)d_in[2];
    const float* Wout = (const float*)d_in[3];
    const float* bout = (const float*)d_in[4];
    float* out = (float*)d_out;

    ushort* qkv   = (ushort*)d_ws;                       // [3][BH][NN][96] bf16
    ushort* ao    = qkv   + (size_t)3 * BH * NN * DHH;   // [8192][768] bf16
    ushort* xbf   = ao    + (size_t)MROWS * DM;          // [8192][768] bf16
    ushort* wqkvt = xbf   + (size_t)MROWS * DM;          // [2304][768] bf16
    ushort* woutt = wqkvt + (size_t)DM * NC_QKV;         // [768][768]  bf16

    dim3 blk(256);

    conv_bf16<<<dim3(MROWS * DM / 8 / 256), blk, 0, stream>>>(x, xbf, MROWS * DM / 8);
    convT2_bf16<<<dim3(DM / 32, (NC_QKV + DM) / 32), blk, 0, stream>>>(
        Wqkv, wqkvt, Wout, woutt);

    gemm_mfma<1><<<dim3(MROWS / 128, NC_QKV / 128), blk, 0, stream>>>(
        xbf, wqkvt, bqkv, (void*)qkv, DM, NC_QKV);

    attn_mfma<<<dim3(16, 32), blk, 0, stream>>>(qkv, ao);

    gemm_mfma<0><<<dim3(MROWS / 128, DM / 128), blk, 0, stream>>>(
        ao, woutt, bout, (void*)out, DM, DM);
}

// Round 19
// 200.481 us; speedup vs baseline: 1.0367x; 1.0367x over previous
//
#include <hip/hip_runtime.h>
#include <hip/hip_bf16.h>
#include <math.h>

// Problem constants
#define BB      4
#define NN      2048
#define DM      768
#define NH      8
#define DHH     96
#define BH      (BB*NH)          // 32
#define MROWS   (BB*NN)          // 8192
#define NC_QKV  (3*DM)           // 2304

typedef short v4s  __attribute__((ext_vector_type(4)));
typedef short v8s  __attribute__((ext_vector_type(8)));
typedef float v4f  __attribute__((ext_vector_type(4)));
typedef float v16f __attribute__((ext_vector_type(16)));
typedef unsigned int u32;

// log2(e)/sqrt(96) folded into Q at QKV-GEMM epilogue
#define SCQ 0.14724599350930152f

static __device__ __forceinline__ ushort f2bf(float f) {
    __hip_bfloat16 h = __float2bfloat16(f);
    return *reinterpret_cast<ushort*>(&h);
}

static __device__ __forceinline__ void gload_lds16(const ushort* g, ushort* l) {
    __builtin_amdgcn_global_load_lds(
        (const __attribute__((address_space(1))) void*)g,
        (__attribute__((address_space(3))) void*)l, 16, 0, 0);
}

// two 8B LDS loads 32B apart -> one v8s A-fragment (k-permutation pi)
static __device__ __forceinline__ v8s load2x4_o16(const ushort* p) {
    union { v4s h[2]; v8s s; } x;
    x.h[0] = *reinterpret_cast<const v4s*>(p);
    x.h[1] = *reinterpret_cast<const v4s*>(p + 16);
    return x.s;
}

static __device__ __forceinline__ v8s pack4(u32 a, u32 b, u32 c, u32 d) {
    union { u32 u[4]; v8s s; } x;
    x.u[0] = a; x.u[1] = b; x.u[2] = c; x.u[3] = d;
    return x.s;
}
static __device__ __forceinline__ u32 bfpair(float lo, float hi) {
    return (u32)f2bf(lo) | ((u32)f2bf(hi) << 16);
}

// ---------------------------------------------------------------------------
// Merged prologue: one launch does BOTH
//   blocks [0, 3072):            x fp32 -> bf16 elementwise (r14 conv body)
//   blocks [3072, 3072+2304):    Wqkv/Wout fp32 -> bf16 transposed (convT2)
// Bodies are byte-identical to the proven kernels; only the launch merges.
// ---------------------------------------------------------------------------
#define CONV_NB   (MROWS * DM / 8 / 256)          // 3072
#define CONVT_NB  ((DM / 32) * ((NC_QKV + DM) / 32))  // 24*96 = 2304

__global__ __launch_bounds__(256)
void prologue_kernel(const float* __restrict__ x, ushort* __restrict__ xbf,
                     const float* __restrict__ Wq, ushort* __restrict__ Wqt,
                     const float* __restrict__ Wo, ushort* __restrict__ Wot)
{
    __shared__ ushort t[32][33];
    const int bid = blockIdx.x;

    if (bid < CONV_NB) {
        // elementwise fp32 -> bf16 (8 elems/thread)
        const int i = bid * 256 + threadIdx.x;
        const float4* p = reinterpret_cast<const float4*>(x) + (size_t)i * 2;
        float4 a = p[0], b = p[1];
        ushort r[8] = {f2bf(a.x), f2bf(a.y), f2bf(a.z), f2bf(a.w),
                       f2bf(b.x), f2bf(b.y), f2bf(b.z), f2bf(b.w)};
        *reinterpret_cast<v8s*>(xbf + (size_t)i * 8) = *reinterpret_cast<v8s*>(r);
        return;
    }

    // weight transpose: decompose (kb, nb)
    const int bid2 = bid - CONV_NB;
    const int kb = bid2 % (DM / 32);        // 0..23
    const int nb = bid2 / (DM / 32);        // 0..95
    const int K = DM;
    const bool isQ = (nb < NC_QKV / 32);
    const float*  W  = isQ ? Wq  : Wo;
    ushort*       Wt = isQ ? Wqt : Wot;
    const int N  = isQ ? NC_QKV : DM;
    const int k0 = kb * 32;
    const int n0 = (isQ ? nb : nb - NC_QKV / 32) * 32;
    const int tx = threadIdx.x & 31, ty = threadIdx.x >> 5;
    #pragma unroll
    for (int r = ty; r < 32; r += 8)
        t[tx][r] = f2bf(W[(size_t)(k0 + r) * N + n0 + tx]);
    __syncthreads();
    #pragma unroll
    for (int r = ty; r < 32; r += 8)
        Wt[(size_t)(n0 + r) * K + k0 + tx] = t[r][tx];
}

// ---------------------------------------------------------------------------
// bf16 MFMA GEMM (round-14/17 form: BK=64, double-buffered global_load_lds
// staging, 2-barrier loop -- the measured-best variant across 5 pipelines)
// ---------------------------------------------------------------------------
template<int SCATTER>
__global__ __launch_bounds__(256)
void gemm_mfma(const ushort* __restrict__ A, const ushort* __restrict__ Bt,
               const float* __restrict__ bias, void* __restrict__ outp,
               int K, int Ncols)
{
    __shared__ ushort As[2][8192];   // [buf][8 kslots][128 rows][8]
    __shared__ ushort Bs[2][8192];

    const int tid  = threadIdx.x;
    const int lane = tid & 63;
    const int wv   = tid >> 6;
    const int l31  = lane & 31;
    const int lhi  = lane >> 5;
    const int wr   = wv >> 1, wc = wv & 1;

    const int ny   = gridDim.y;
    const int id   = blockIdx.y * gridDim.x + blockIdx.x;
    const int c8   = id & 7;
    const int j    = id >> 3;
    const int hy   = (j >= (ny >> 1) * 8) ? 1 : 0;
    const int w    = j - hy * (ny >> 1) * 8;
    const int bx   = c8 * 8 + (w & 7);
    const int by   = hy * (ny >> 1) + (w >> 3);
    const int row0 = bx * 128;
    const int col0 = by * 128;

    v16f acc[2][2];
    #pragma unroll
    for (int mi = 0; mi < 2; ++mi)
        #pragma unroll
        for (int nj = 0; nj < 2; ++nj)
            #pragma unroll
            for (int i = 0; i < 16; ++i) acc[mi][nj][i] = 0.0f;

#define STAGE_G(bsel, kk) do {                                                  \
    _Pragma("unroll")                                                           \
    for (int c = 0; c < 4; ++c) {                                               \
        const int g   = c * 4 + wv;                                             \
        const int idx = g * 64 + lane;                                          \
        const int ss  = idx >> 7, rr = idx & 127;                               \
        gload_lds16(&A [(size_t)(row0 + rr) * K + (kk) + ss * 8],               \
                    &As[bsel][g * 512]);                                        \
        gload_lds16(&Bt[(size_t)(col0 + rr) * K + (kk) + ss * 8],               \
                    &Bs[bsel][g * 512]);                                        \
    }                                                                           \
} while (0)

    STAGE_G(0, 0);
    __syncthreads();

    const int nk = K >> 6;
    for (int t = 0; t < nk; ++t) {
        const int cur = t & 1;
        if (t + 1 < nk) STAGE_G(cur ^ 1, (t + 1) << 6);

        #pragma unroll
        for (int s16 = 0; s16 < 4; ++s16) {
            const int ks = s16 * 2 + lhi;
            v8s a0 = *reinterpret_cast<const v8s*>(&As[cur][(size_t)(ks * 128 + 64 * wr + l31) * 8]);
            v8s a1 = *reinterpret_cast<const v8s*>(&As[cur][(size_t)(ks * 128 + 64 * wr + 32 + l31) * 8]);
            v8s b0 = *reinterpret_cast<const v8s*>(&Bs[cur][(size_t)(ks * 128 + 64 * wc + l31) * 8]);
            v8s b1 = *reinterpret_cast<const v8s*>(&Bs[cur][(size_t)(ks * 128 + 64 * wc + 32 + l31) * 8]);
            acc[0][0] = __builtin_amdgcn_mfma_f32_32x32x16_bf16(a0, b0, acc[0][0], 0, 0, 0);
            acc[0][1] = __builtin_amdgcn_mfma_f32_32x32x16_bf16(a0, b1, acc[0][1], 0, 0, 0);
            acc[1][0] = __builtin_amdgcn_mfma_f32_32x32x16_bf16(a1, b0, acc[1][0], 0, 0, 0);
            acc[1][1] = __builtin_amdgcn_mfma_f32_32x32x16_bf16(a1, b1, acc[1][1], 0, 0, 0);
        }
        __syncthreads();
    }
#undef STAGE_G

    #pragma unroll
    for (int nj = 0; nj < 2; ++nj) {
        const int c = col0 + 64 * wc + 32 * nj + l31;
        const float bv = bias[c];
        #pragma unroll
        for (int mi = 0; mi < 2; ++mi) {
            #pragma unroll
            for (int r = 0; r < 16; ++r) {
                const int m = row0 + 64 * wr + 32 * mi + (r & 3) + 8 * (r >> 2) + 4 * lhi;
                float v = acc[mi][nj][r] + bv;
                if (SCATTER) {
                    const int s   = c / DM;
                    const int rem = c - s * DM;
                    const int h   = rem / DHH;
                    const int d   = rem - h * DHH;
                    const int b   = m >> 11;
                    const int n   = m & (NN - 1);
                    if (s == 0) v *= SCQ;
                    ((ushort*)outp)[((size_t)(s * BH + b * NH + h) * NN + n) * DHH + d] = f2bf(v);
                } else {
                    ((float*)outp)[(size_t)m * Ncols + c] = v;
                }
            }
        }
    }
}

// ---------------------------------------------------------------------------
// MFMA bf16 flash attention (round-14 kernel, frozen: best measured, 94us).
// 16x16x32, 2 q-tiles/wave, exchange-free P via pi(g4,i)=g4*4+(i&3)+16*(i>>2),
// single-buffered K/V, scalar-b16 V transpose (conflicts==0).
// ---------------------------------------------------------------------------
__global__ __launch_bounds__(256, 2)
void attn_mfma(const ushort* __restrict__ qkv, ushort* __restrict__ attnout)
{
    __shared__ ushort Ks[6144];        // [g=d/8:12][kv=64][8]
    __shared__ ushort Vt[96][68];      // [d][kv], pad 68 (conflict-free)

    const int tid  = threadIdx.x;
    const int lane = tid & 63;
    const int wv   = tid >> 6;          // 0..3
    const int l15  = lane & 15;
    const int g4   = lane >> 4;         // 0..3

    // bh-clustered XCD swizzle (grid = (16 qblk, 32 bh)): 4 bh per XCD
    const int id   = blockIdx.y * gridDim.x + blockIdx.x;   // 0..511
    const int c8   = id & 7;
    const int j    = id >> 3;            // 0..63
    const int bh   = c8 * 4 + (j & 3);
    const int qblk = j >> 2;             // 0..15
    const int q0   = qblk * 128;
    const int b    = bh >> 3, h = bh & 7;

    const ushort* Qg = qkv + (size_t)bh * NN * DHH;
    const ushort* Kg = qkv + ((size_t)BH + bh) * NN * DHH;
    const ushort* Vg = qkv + ((size_t)2 * BH + bh) * NN * DHH;

    v8s qf[2][3];
    #pragma unroll
    for (int qt = 0; qt < 2; ++qt)
        #pragma unroll
        for (int c = 0; c < 3; ++c)
            qf[qt][c] = *reinterpret_cast<const v8s*>(
                &Qg[(size_t)(q0 + wv * 32 + qt * 16 + l15) * DHH + c * 32 + g4 * 8]);

    v4f o[2][6];
    #pragma unroll
    for (int qt = 0; qt < 2; ++qt)
        #pragma unroll
        for (int dt = 0; dt < 6; ++dt)
            #pragma unroll
            for (int i = 0; i < 4; ++i) o[qt][dt][i] = 0.0f;
    float ds[2] = {0.0f, 0.0f};

    // ---- prologue: stage tile 0 -> LDS
    {
        const size_t rowb = (size_t)lane * DHH;
        v8s kr[3], vr[3];
        #pragma unroll
        for (int i = 0; i < 3; ++i) {
            kr[i] = *reinterpret_cast<const v8s*>(&Kg[rowb + (wv * 3 + i) * 8]);
            vr[i] = *reinterpret_cast<const v8s*>(&Vg[rowb + (i * 4 + wv) * 8]);
        }
        #pragma unroll
        for (int i = 0; i < 3; ++i) {
            *reinterpret_cast<v8s*>(&Ks[(wv * 3 + i) * 512 + lane * 8]) = kr[i];
            #pragma unroll
            for (int jj = 0; jj < 8; ++jj)
                Vt[(i * 4 + wv) * 8 + jj][lane] = (ushort)vr[i][jj];
        }
    }
    __syncthreads();

    for (int t = 0; t < 32; ++t) {
        v8s kr0, kr1, kr2, vr0, vr1, vr2;
        if (t < 31) {
            const size_t rowb = (size_t)((t + 1) * 64 + lane) * DHH;
            kr0 = *reinterpret_cast<const v8s*>(&Kg[rowb + (wv * 3 + 0) * 8]);
            kr1 = *reinterpret_cast<const v8s*>(&Kg[rowb + (wv * 3 + 1) * 8]);
            kr2 = *reinterpret_cast<const v8s*>(&Kg[rowb + (wv * 3 + 2) * 8]);
            vr0 = *reinterpret_cast<const v8s*>(&Vg[rowb + (0 * 4 + wv) * 8]);
            vr1 = *reinterpret_cast<const v8s*>(&Vg[rowb + (1 * 4 + wv) * 8]);
            vr2 = *reinterpret_cast<const v8s*>(&Vg[rowb + (2 * 4 + wv) * 8]);
        }

        #pragma unroll
        for (int th = 0; th < 2; ++th) {
            v4f s00, s01, s10, s11;
            #pragma unroll
            for (int i = 0; i < 4; ++i) {
                s00[i] = 0.0f; s01[i] = 0.0f; s10[i] = 0.0f; s11[i] = 0.0f;
            }
            __builtin_amdgcn_s_setprio(1);
            #pragma unroll
            for (int c = 0; c < 3; ++c) {
                v8s kf0 = *reinterpret_cast<const v8s*>(
                    &Ks[((c * 4 + g4) * 64 + (th * 2 + 0) * 16 + l15) * 8]);
                v8s kf1 = *reinterpret_cast<const v8s*>(
                    &Ks[((c * 4 + g4) * 64 + (th * 2 + 1) * 16 + l15) * 8]);
                s00 = __builtin_amdgcn_mfma_f32_16x16x32_bf16(kf0, qf[0][c], s00, 0, 0, 0);
                s01 = __builtin_amdgcn_mfma_f32_16x16x32_bf16(kf1, qf[0][c], s01, 0, 0, 0);
                s10 = __builtin_amdgcn_mfma_f32_16x16x32_bf16(kf0, qf[1][c], s10, 0, 0, 0);
                s11 = __builtin_amdgcn_mfma_f32_16x16x32_bf16(kf1, qf[1][c], s11, 0, 0, 0);
            }
            __builtin_amdgcn_s_setprio(0);

            v8s pf[2];
            #pragma unroll
            for (int qt = 0; qt < 2; ++qt) {
                const v4f& sa = qt ? s10 : s00;
                const v4f& sb = qt ? s11 : s01;
                float e0[4], e1[4];
                #pragma unroll
                for (int r = 0; r < 4; ++r) {
                    e0[r] = exp2f(sa[r]);
                    e1[r] = exp2f(sb[r]);
                    ds[qt] += e0[r] + e1[r];
                }
                pf[qt] = pack4(bfpair(e0[0], e0[1]), bfpair(e0[2], e0[3]),
                               bfpair(e1[0], e1[1]), bfpair(e1[2], e1[3]));
            }

            __builtin_amdgcn_s_setprio(1);
            #pragma unroll
            for (int dt = 0; dt < 6; ++dt) {
                const ushort* vp = &Vt[dt * 16 + l15][th * 32 + g4 * 4];
                v8s va = load2x4_o16(vp);
                o[0][dt] = __builtin_amdgcn_mfma_f32_16x16x32_bf16(va, pf[0], o[0][dt], 0, 0, 0);
                o[1][dt] = __builtin_amdgcn_mfma_f32_16x16x32_bf16(va, pf[1], o[1][dt], 0, 0, 0);
            }
            __builtin_amdgcn_s_setprio(0);
        }

        if (t < 31) {
            __syncthreads();
            *reinterpret_cast<v8s*>(&Ks[(wv * 3 + 0) * 512 + lane * 8]) = kr0;
            *reinterpret_cast<v8s*>(&Ks[(wv * 3 + 1) * 512 + lane * 8]) = kr1;
            *reinterpret_cast<v8s*>(&Ks[(wv * 3 + 2) * 512 + lane * 8]) = kr2;
            #pragma unroll
            for (int jj = 0; jj < 8; ++jj) Vt[(0 * 4 + wv) * 8 + jj][lane] = (ushort)vr0[jj];
            #pragma unroll
            for (int jj = 0; jj < 8; ++jj) Vt[(1 * 4 + wv) * 8 + jj][lane] = (ushort)vr1[jj];
            #pragma unroll
            for (int jj = 0; jj < 8; ++jj) Vt[(2 * 4 + wv) * 8 + jj][lane] = (ushort)vr2[jj];
            __syncthreads();
        }
    }

    #pragma unroll
    for (int qt = 0; qt < 2; ++qt) {
        float d = ds[qt];
        d += __shfl_xor(d, 16, 64);
        d += __shfl_xor(d, 32, 64);
        const float inv = 1.0f / d;
        const int n = q0 + wv * 32 + qt * 16 + l15;
        ushort* orow = attnout + ((size_t)(b * NN + n)) * DM + h * DHH;
        #pragma unroll
        for (int dt = 0; dt < 6; ++dt) {
            const int d0 = dt * 16 + g4 * 4;
            uint2 pk;
            pk.x = bfpair(o[qt][dt][0] * inv, o[qt][dt][1] * inv);
            pk.y = bfpair(o[qt][dt][2] * inv, o[qt][dt][3] * inv);
            *reinterpret_cast<uint2*>(&orow[d0]) = pk;
        }
    }
}

// ---------------------------------------------------------------------------
extern "C" void kernel_launch(void* const* d_in, const int* in_sizes, int n_in,
                              void* d_out, int out_size, void* d_ws, size_t ws_size,
                              hipStream_t stream)
{
    (void)in_sizes; (void)n_in; (void)out_size; (void)ws_size;
    const float* x    = (const float*)d_in[0];
    const float* Wqkv = (const float*)d_in[1];
    const float* bqkv = (const float*)d_in[2];
    const float* Wout = (const float*)d_in[3];
    const float* bout = (const float*)d_in[4];
    float* out = (float*)d_out;

    ushort* qkv   = (ushort*)d_ws;                       // [3][BH][NN][96] bf16
    ushort* ao    = qkv   + (size_t)3 * BH * NN * DHH;   // [8192][768] bf16
    ushort* xbf   = ao    + (size_t)MROWS * DM;          // [8192][768] bf16
    ushort* wqkvt = xbf   + (size_t)MROWS * DM;          // [2304][768] bf16
    ushort* woutt = wqkvt + (size_t)DM * NC_QKV;         // [768][768]  bf16

    dim3 blk(256);

    prologue_kernel<<<dim3(CONV_NB + CONVT_NB), blk, 0, stream>>>(
        x, xbf, Wqkv, wqkvt, Wout, woutt);

    gemm_mfma<1><<<dim3(MROWS / 128, NC_QKV / 128), blk, 0, stream>>>(
        xbf, wqkvt, bqkv, (void*)qkv, DM, NC_QKV);

    attn_mfma<<<dim3(16, 32), blk, 0, stream>>>(qkv, ao);

    gemm_mfma<0><<<dim3(MROWS / 128, DM / 128), blk, 0, stream>>>(
        ao, woutt, bout, (void*)out, DM, DM);
}